// Round 4
// baseline (147.325 us; speedup 1.0000x reference)
//
#include <hip/hip_runtime.h>
#include <math.h>

// Problem constants (fixed by the reference).
constexpr int BATCH = 4;
constexpr int SEQ   = 2048;
constexpr int NEMB  = 1024;
constexpr int HS    = 64;

typedef __attribute__((ext_vector_type(8))) short short8;   // MFMA A/B frag (8 bf16)
typedef __attribute__((ext_vector_type(4))) float f32x4;    // MFMA C/D frag
typedef __attribute__((ext_vector_type(4))) float fv4;      // native vec for NT loads

// fp32 -> bf16 bits, round-to-nearest-even
__device__ inline unsigned short f2bf(float f) {
    unsigned u = __builtin_bit_cast(unsigned, f);
    u += 0x7fffu + ((u >> 16) & 1u);
    return (unsigned short)(u >> 16);
}
__device__ inline unsigned long long pack4bf(float a, float b, float c, float d) {
    return (unsigned long long)(f2bf(a) | ((unsigned)f2bf(b) << 16)) |
           ((unsigned long long)(f2bf(c) | ((unsigned)f2bf(d) << 16)) << 32);
}

// async 16B global->LDS (direct-to-shared DMA); LDS dest = wave-uniform base + lane*16
__device__ inline void gll16(const void* g, void* l) {
    __builtin_amdgcn_global_load_lds((const __attribute__((address_space(1))) void*)g,
                                     (__attribute__((address_space(3))) void*)l, 16, 0, 0);
}
#define WAIT_VM0()   asm volatile("s_waitcnt vmcnt(0)" ::: "memory")
#define WAIT_VM8()   asm volatile("s_waitcnt vmcnt(8)" ::: "memory")
#define WAIT_LGKM0() asm volatile("s_waitcnt lgkmcnt(0)" ::: "memory")

// ---------------------------------------------------------------------------
// Kernel 0: one-time W fp32 -> bf16 (wbf[192][1024], rows = q|k|v heads).
// ---------------------------------------------------------------------------
__launch_bounds__(256) __global__
void conv_w(const float* __restrict__ Wq, const float* __restrict__ Wk,
            const float* __restrict__ Wv, unsigned short* __restrict__ wbf)
{
    const int idx = (blockIdx.x * 256 + threadIdx.x) * 8;   // 8 floats/thread
    const int row = idx >> 10, col = idx & 1023;
    const float* src = (row < 64) ? (Wq + (size_t)row * NEMB)
                     : (row < 128) ? (Wk + (size_t)(row - 64) * NEMB)
                                   : (Wv + (size_t)(row - 128) * NEMB);
    float4 a = *(const float4*)(src + col);
    float4 b = *(const float4*)(src + col + 4);
    *(unsigned long long*)(wbf + idx)     = pack4bf(a.x, a.y, a.z, a.w);
    *(unsigned long long*)(wbf + idx + 4) = pack4bf(b.x, b.y, b.z, b.w);
}

// ---------------------------------------------------------------------------
// Kernel 1: QKV projection — NO LDS, NO barriers. BM=16, 512 blocks x 4 waves.
// Wave w computes n-tiles {w*48, w*48+16, w*48+32} over C[8192,192].
// A-frags from fp32 x via NONTEMPORAL loads (x is read once; keep L2 for W,
// which is re-read 512x); B-frags from bf16 W copy (L2-resident).
// ---------------------------------------------------------------------------
__launch_bounds__(256) __global__
void qkv_proj(const float* __restrict__ x, const unsigned short* __restrict__ wbf,
              unsigned short* __restrict__ qb, unsigned short* __restrict__ kb,
              unsigned short* __restrict__ vtb)
{
    const int m0   = blockIdx.x * 16;
    const int tid  = threadIdx.x;
    const int w    = tid >> 6;
    const int lane = tid & 63;
    const int quad = lane >> 4;
    const int c    = lane & 15;

    f32x4 acc[3];
#pragma unroll
    for (int j = 0; j < 3; ++j) acc[j] = (f32x4){0.f, 0.f, 0.f, 0.f};

    const fv4* xrow = (const fv4*)(x + (size_t)(m0 + c) * NEMB + quad * 8);
    const unsigned short* wrow = wbf + (size_t)(w * 48 + c) * NEMB + quad * 8;

    union { short8 s8; unsigned long long u[2]; } af;
#pragma unroll 8
    for (int k0 = 0; k0 < NEMB; k0 += 32) {
        fv4 a0 = __builtin_nontemporal_load(xrow + (k0 >> 2));
        fv4 a1 = __builtin_nontemporal_load(xrow + (k0 >> 2) + 1);
        af.u[0] = pack4bf(a0.x, a0.y, a0.z, a0.w);
        af.u[1] = pack4bf(a1.x, a1.y, a1.z, a1.w);
#pragma unroll
        for (int j = 0; j < 3; ++j) {
            short8 bf = *(const short8*)(wrow + (size_t)j * 16 * NEMB + k0);
            acc[j] = __builtin_amdgcn_mfma_f32_16x16x32_bf16(af.s8, bf, acc[j], 0, 0, 0);
        }
    }

    // Epilogue. C layout: row = quad*4+reg (m), col = c (n).
    const int mrow = m0 + quad * 4;
#pragma unroll
    for (int j = 0; j < 3; ++j) {
        const int n = w * 48 + j * 16 + c;
        if (n < 128) {          // q or k: row-major [bt][64] bf16
            unsigned short* dst = (n < 64) ? (qb + n) : (kb + (n - 64));
#pragma unroll
            for (int r = 0; r < 4; ++r)
                dst[(size_t)(mrow + r) * HS] = f2bf(acc[j][r]);
        } else {                // v: transposed [b][h][t] bf16, 4 consecutive t
            const int h  = n - 128;
            const int bb = mrow >> 11;
            const int t0 = mrow & 2047;
            *(unsigned long long*)(vtb + ((size_t)bb << 17) + ((size_t)h << 11) + t0) =
                pack4bf(acc[j][0], acc[j][1], acc[j][2], acc[j][3]);
        }
    }
}

// ---------------------------------------------------------------------------
// Kernel 2: MFMA flash attention — DOUBLE-BUFFERED per-wave DMA pipeline.
// Block = 4 waves, one 16-query tile; wave si owns 32-key tiles st==si (mod 4)
// with private softmax state and a private 16 KB LDS slice (2 bufs x 8 KB).
// Steady state: wait vmcnt(8) [tile j landed, tile j+1 still in flight] ->
// compute j -> lgkmcnt(0) -> issue DMA for tile j+2 into buf j&1. The DMA for
// j+1 has a whole compute phase to land -> latency hidden (cp.async-style).
// Chunk-XOR swizzles keep every b128 read <=2-way (free) bank aliasing.
// ---------------------------------------------------------------------------
__launch_bounds__(256) __global__
void attn(const unsigned short* __restrict__ qg, const unsigned short* __restrict__ kg,
          const unsigned short* __restrict__ vtg, float* __restrict__ out)
{
    __shared__ __align__(16) char smem[71168];
    // per-wave slice @ si*16384: buf p at +p*8192 = K[32][64] (4KB) | V^T[64][32] (4KB)
    auto Ps  = (unsigned short(*)[40])(smem + 65536);   // [64][40] bf16 (5120 B)
    float* msl = (float*)(smem + 70656);                // m[4][16] | l[4][16] (512 B)
    auto Oc  = (float(*)[68])smem;                      // [64][68] fp32, overlaps K/V

    const int b    = blockIdx.y;
    const int qt   = (int)gridDim.x - 1 - (int)blockIdx.x;  // heavy tiles first
    const int q0   = qt * 16;
    const int tid  = threadIdx.x;
    const int si   = tid >> 6;
    const int lane = tid & 63;
    const int quad = lane >> 4;
    const int c    = lane & 15;

    char* kv = smem + si * 16384;

    // Q fragments in registers for the whole kernel. A[m=c][k=quad*8+j].
    const unsigned short* qrow = qg + (size_t)(b * SEQ + q0 + c) * HS;
    const short8 qa0 = *(const short8*)(qrow + quad * 8);
    const short8 qa1 = *(const short8*)(qrow + 32 + quad * 8);
    WAIT_VM0();   // drain Q loads so vmcnt counts ONLY our DMA below

    float m_st[4], l_st[4];
    f32x4 O[4];
#pragma unroll
    for (int r = 0; r < 4; ++r) { m_st[r] = -INFINITY; l_st[r] = 0.f; }
#pragma unroll
    for (int ht = 0; ht < 4; ++ht) O[ht] = (f32x4){0.f, 0.f, 0.f, 0.f};

    const int nTilesTot = (q0 + 16 + 31) >> 5;          // 32-key tiles (causal)
    const int nT = (nTilesTot - si + 3) >> 2;           // this wave's tile count

    // stage tile st=si+4*j into buf p: 8 async 1KB DMA loads, chunk-swizzled
    auto issue = [&](int j, int p) {
        const int key0 = (si + 4 * j) * 32;
        const unsigned short* kgb = kg + (size_t)(b * SEQ + key0) * HS;
        char* dstK = kv + p * 8192;
#pragma unroll
        for (int i = 0; i < 4; ++i) {            // K[32 keys][64 h]
            const int f = i * 64 + lane, row = f >> 3, ch = f & 7;
            gll16(kgb + (size_t)row * HS + ((ch ^ (row & 7)) * 8), dstK + i * 1024);
        }
        const unsigned short* vgb = vtg + ((size_t)b << 17) + key0;
        char* dstV = kv + p * 8192 + 4096;
#pragma unroll
        for (int i = 0; i < 4; ++i) {            // V^T[64 h][32 t]
            const int f = i * 64 + lane, h = f >> 2, ch = f & 3;
            const int cs = ch ^ (h & 3) ^ ((h >> 2) & 3);
            gll16(vgb + ((size_t)h << 11) + cs * 8, dstV + i * 1024);
        }
    };

    if (nT > 0) issue(0, 0);
    if (nT > 1) issue(1, 1);

    for (int j = 0; j < nT; ++j) {
        if (j + 1 < nT) { WAIT_VM8(); } else { WAIT_VM0(); }   // tile j landed
        const int st = si + 4 * j, key0 = st * 32, p = j & 1;
        const unsigned short* Kb = (const unsigned short*)(kv + p * 8192);
        const unsigned short* Vb = (const unsigned short*)(kv + p * 8192 + 4096);
        const bool masked = (st == nTilesTot - 1);

        // ---- S = Q K^T * scale (C layout: row=q=quad*4+r, col=key=nt*16+c) ----
        f32x4 sc[2];
#pragma unroll
        for (int nt = 0; nt < 2; ++nt) {
            const int kr = nt * 16 + c;
            short8 kb0 = *(const short8*)(Kb + kr * 64 + ((quad)     ^ (kr & 7)) * 8);
            short8 kb1 = *(const short8*)(Kb + kr * 64 + ((4 + quad) ^ (kr & 7)) * 8);
            f32x4 s = (f32x4){0.f, 0.f, 0.f, 0.f};
            s = __builtin_amdgcn_mfma_f32_16x16x32_bf16(qa0, kb0, s, 0, 0, 0);
            s = __builtin_amdgcn_mfma_f32_16x16x32_bf16(qa1, kb1, s, 0, 0, 0);
            sc[nt] = s * 0.125f;
            if (masked) {
                const int sglob = key0 + kr;
#pragma unroll
                for (int r = 0; r < 4; ++r)
                    if (sglob > q0 + quad * 4 + r) sc[nt][r] = -INFINITY;
            }
        }
        // ---- online softmax per row (reduce across 16 lanes of the quad) ----
#pragma unroll
        for (int r = 0; r < 4; ++r) {
            float v = fmaxf(sc[0][r], sc[1][r]);
            v = fmaxf(v, __shfl_xor(v, 1));
            v = fmaxf(v, __shfl_xor(v, 2));
            v = fmaxf(v, __shfl_xor(v, 4));
            v = fmaxf(v, __shfl_xor(v, 8));
            const float mnew  = fmaxf(m_st[r], v);
            const float alpha = __expf(m_st[r] - mnew);
            const float p0 = __expf(sc[0][r] - mnew);
            const float p1 = __expf(sc[1][r] - mnew);
            float sum = p0 + p1;
            sum += __shfl_xor(sum, 1);
            sum += __shfl_xor(sum, 2);
            sum += __shfl_xor(sum, 4);
            sum += __shfl_xor(sum, 8);
            l_st[r] = l_st[r] * alpha + sum;
            m_st[r] = mnew;
#pragma unroll
            for (int ht = 0; ht < 4; ++ht) O[ht][r] *= alpha;
            const int prow = si * 16 + quad * 4 + r;
            Ps[prow][c]      = f2bf(p0);
            Ps[prow][16 + c] = f2bf(p1);
        }
        // ---- O += P V : single b128 A-frag (k=32); V^T rows swizzled ----
        short8 pa = *(const short8*)&Ps[si * 16 + c][quad * 8];
#pragma unroll
        for (int ht = 0; ht < 4; ++ht) {
            const int vr  = ht * 16 + c;
            const int pos = quad ^ (vr & 3) ^ ((vr >> 2) & 3);
            short8 vb = *(const short8*)(Vb + vr * 32 + pos * 8);
            O[ht] = __builtin_amdgcn_mfma_f32_16x16x32_bf16(pa, vb, O[ht], 0, 0, 0);
        }
        WAIT_LGKM0();                       // ds reads done before buf reuse
        if (j + 2 < nT) issue(j + 2, p);    // prefetch into the buf just freed
    }

    // ---- cross-wave combine (the only barriers in the kernel) ----
    if (c == 0) {
#pragma unroll
        for (int r = 0; r < 4; ++r) {
            msl[si * 16 + quad * 4 + r]      = m_st[r];
            msl[64 + si * 16 + quad * 4 + r] = l_st[r];
        }
    }
    __syncthreads();
#pragma unroll
    for (int r = 0; r < 4; ++r) {
        const int row = quad * 4 + r;
        float M = fmaxf(fmaxf(msl[row], msl[16 + row]),
                        fmaxf(msl[32 + row], msl[48 + row]));
        const float scw = __expf(m_st[r] - M);   // 0 for idle waves (m=-inf)
#pragma unroll
        for (int ht = 0; ht < 4; ++ht)
            Oc[si * 16 + row][ht * 16 + c] = O[ht][r] * scw;
    }
    __syncthreads();
    {
        const int row = tid >> 4, hb = (tid & 15) * 4;
        float M = fmaxf(fmaxf(msl[row], msl[16 + row]),
                        fmaxf(msl[32 + row], msl[48 + row]));
        float L = 0.f;
#pragma unroll
        for (int w = 0; w < 4; ++w)
            L += __expf(msl[w * 16 + row] - M) * msl[64 + w * 16 + row];
        float ax = 0.f, ay = 0.f, az = 0.f, aw = 0.f;
#pragma unroll
        for (int w = 0; w < 4; ++w) {
            const float4 t = *(const float4*)&Oc[w * 16 + row][hb];
            ax += t.x; ay += t.y; az += t.z; aw += t.w;
        }
        const float inv = 1.f / L;
        *(float4*)(out + (size_t)(b * SEQ + q0 + row) * HS + hb) =
            make_float4(ax * inv, ay * inv, az * inv, aw * inv);
    }
}

// ---------------------------------------------------------------------------
extern "C" void kernel_launch(void* const* d_in, const int* in_sizes, int n_in,
                              void* d_out, int out_size, void* d_ws, size_t ws_size,
                              hipStream_t stream)
{
    const float* x  = (const float*)d_in[0];
    const float* Wq = (const float*)d_in[1];
    const float* Wk = (const float*)d_in[2];
    const float* Wv = (const float*)d_in[3];

    // ws: q bf16 [bt][64] | k bf16 [bt][64] | v^T bf16 [b][h][t] | W bf16 [192][1024]
    unsigned short* qb  = (unsigned short*)d_ws;
    unsigned short* kb  = qb  + (size_t)BATCH * SEQ * HS;
    unsigned short* vtb = kb  + (size_t)BATCH * SEQ * HS;
    unsigned short* wbf = vtb + (size_t)BATCH * SEQ * HS;

    conv_w  <<<dim3(96),                dim3(256), 0, stream>>>(Wq, Wk, Wv, wbf);
    qkv_proj<<<dim3(BATCH * SEQ / 16),  dim3(256), 0, stream>>>(x, wbf, qb, kb, vtb);
    attn    <<<dim3(SEQ / 16, BATCH),   dim3(256), 0, stream>>>(qb, kb, vtb, (float*)d_out);
}

// Round 5
// 137.911 us; speedup vs baseline: 1.0683x; 1.0683x over previous
//
#include <hip/hip_runtime.h>
#include <math.h>

// Problem constants (fixed by the reference).
constexpr int BATCH = 4;
constexpr int SEQ   = 2048;
constexpr int NEMB  = 1024;
constexpr int HS    = 64;

typedef __attribute__((ext_vector_type(8))) short short8;   // MFMA A/B frag (8 bf16)
typedef __attribute__((ext_vector_type(4))) float f32x4;    // MFMA C/D frag
typedef __attribute__((ext_vector_type(4))) float fv4;      // native vec for NT loads

// fp32 -> bf16 bits, round-to-nearest-even
__device__ inline unsigned short f2bf(float f) {
    unsigned u = __builtin_bit_cast(unsigned, f);
    u += 0x7fffu + ((u >> 16) & 1u);
    return (unsigned short)(u >> 16);
}
__device__ inline unsigned long long pack4bf(float a, float b, float c, float d) {
    return (unsigned long long)(f2bf(a) | ((unsigned)f2bf(b) << 16)) |
           ((unsigned long long)(f2bf(c) | ((unsigned)f2bf(d) << 16)) << 32);
}

// async 16B global->LDS (direct-to-shared DMA); LDS dest = wave-uniform base + lane*16
__device__ inline void gll16(const void* g, void* l) {
    __builtin_amdgcn_global_load_lds((const __attribute__((address_space(1))) void*)g,
                                     (__attribute__((address_space(3))) void*)l, 16, 0, 0);
}
#define WAIT_VM0()   asm volatile("s_waitcnt vmcnt(0)" ::: "memory")
#define WAIT_VM8()   asm volatile("s_waitcnt vmcnt(8)" ::: "memory")
#define WAIT_LGKM0() asm volatile("s_waitcnt lgkmcnt(0)" ::: "memory")

// ---------------------------------------------------------------------------
// Kernel 0: pack x AND W into MFMA-fragment-tiled bf16 layout.
// Tiled layout, per 16-row tile: elem offset = (kc*16 + r)*8 + j  where the
// original element is (row = tile*16 + r, k = kc*8 + j). A wave b128-load of
// a fragment [(kc0+quad)*16 + c] then covers ONE contiguous 1 KB span.
// Blocks 0..511: x tiles. Blocks 512..523: W tiles (q|k|v, 4 tiles each).
// ---------------------------------------------------------------------------
__launch_bounds__(256) __global__
void pack_tiles(const float* __restrict__ x,  const float* __restrict__ Wq,
                const float* __restrict__ Wk, const float* __restrict__ Wv,
                unsigned short* __restrict__ xbt, unsigned short* __restrict__ wt)
{
    const int bid = blockIdx.x;
    const int t   = threadIdx.x;
    char* dst = (bid < 512) ? (char*)(xbt + (size_t)bid * 16384)
                            : (char*)(wt + (size_t)(bid - 512) * 16384);
    // per row: thread t handles float4 #t (4 k's); write 8B to tiled position
    const size_t woff = (size_t)(t >> 1) * 256 + (t & 1) * 8;
#pragma unroll 4
    for (int i = 0; i < 16; ++i) {
        const float* src;
        if (bid < 512) {
            src = x + ((size_t)bid * 16 + i) * NEMB;
        } else {
            const int wi = bid - 512, sel = wi >> 2, lr = (wi & 3) * 16 + i;
            const float* W = (sel == 0) ? Wq : (sel == 1) ? Wk : Wv;
            src = W + (size_t)lr * NEMB;
        }
        fv4 v = __builtin_nontemporal_load((const fv4*)src + t);
        *(unsigned long long*)(dst + woff + (size_t)i * 16) =
            pack4bf(v.x, v.y, v.z, v.w);
    }
}

// ---------------------------------------------------------------------------
// Kernel 1: QKV projection — NO LDS, NO barriers, NO pack VALU.
// BM=16, 512 blocks x 4 waves; wave w owns n-tiles {3w,3w+1,3w+2} of 12
// (n rows of C = q|k|v heads). Every A/B fragment load is one contiguous
// 1 KB wave b128 from the tiled buffers; loads are independent & linear ->
// deep compiler pipelining. B (wt, 384 KB) is L2-resident.
// ---------------------------------------------------------------------------
__launch_bounds__(256) __global__
void qkv_proj(const unsigned short* __restrict__ xbt, const unsigned short* __restrict__ wt,
              unsigned short* __restrict__ qb, unsigned short* __restrict__ kb,
              unsigned short* __restrict__ vtb)
{
    const int mt   = blockIdx.x;
    const int m0   = mt * 16;
    const int tid  = threadIdx.x;
    const int w    = tid >> 6;
    const int lane = tid & 63;
    const int quad = lane >> 4;
    const int c    = lane & 15;

    f32x4 acc[3];
#pragma unroll
    for (int j = 0; j < 3; ++j) acc[j] = (f32x4){0.f, 0.f, 0.f, 0.f};

    const unsigned short* ab = xbt + (size_t)mt * 16384 + quad * 128 + c * 8;
    const unsigned short* bb = wt + (size_t)(w * 3) * 16384 + quad * 128 + c * 8;

#pragma unroll 4
    for (int kc0 = 0; kc0 < 128; kc0 += 4) {     // k0 = kc0*8, K-step 32
        short8 a = *(const short8*)(ab + (size_t)kc0 * 128);
#pragma unroll
        for (int j = 0; j < 3; ++j) {
            short8 bf = *(const short8*)(bb + (size_t)j * 16384 + (size_t)kc0 * 128);
            acc[j] = __builtin_amdgcn_mfma_f32_16x16x32_bf16(a, bf, acc[j], 0, 0, 0);
        }
    }

    // Epilogue. C layout: row = quad*4+reg (m), col = c (n).
    const int mrow = m0 + quad * 4;
#pragma unroll
    for (int j = 0; j < 3; ++j) {
        const int n = w * 48 + j * 16 + c;
        if (n < 128) {          // q or k: row-major [bt][64] bf16
            unsigned short* dst = (n < 64) ? (qb + n) : (kb + (n - 64));
#pragma unroll
            for (int r = 0; r < 4; ++r)
                dst[(size_t)(mrow + r) * HS] = f2bf(acc[j][r]);
        } else {                // v: transposed [b][h][t] bf16, 4 consecutive t
            const int h  = n - 128;
            const int bb2 = mrow >> 11;
            const int t0 = mrow & 2047;
            *(unsigned long long*)(vtb + ((size_t)bb2 << 17) + ((size_t)h << 11) + t0) =
                pack4bf(acc[j][0], acc[j][1], acc[j][2], acc[j][3]);
        }
    }
}

// ---------------------------------------------------------------------------
// Kernel 2: MFMA flash attention — double-buffered per-wave DMA pipeline.
// (unchanged from round 4; see comments there)
// ---------------------------------------------------------------------------
__launch_bounds__(256) __global__
void attn(const unsigned short* __restrict__ qg, const unsigned short* __restrict__ kg,
          const unsigned short* __restrict__ vtg, float* __restrict__ out)
{
    __shared__ __align__(16) char smem[71168];
    auto Ps  = (unsigned short(*)[40])(smem + 65536);   // [64][40] bf16 (5120 B)
    float* msl = (float*)(smem + 70656);                // m[4][16] | l[4][16] (512 B)
    auto Oc  = (float(*)[68])smem;                      // [64][68] fp32, overlaps K/V

    const int b    = blockIdx.y;
    const int qt   = (int)gridDim.x - 1 - (int)blockIdx.x;  // heavy tiles first
    const int q0   = qt * 16;
    const int tid  = threadIdx.x;
    const int si   = tid >> 6;
    const int lane = tid & 63;
    const int quad = lane >> 4;
    const int c    = lane & 15;

    char* kv = smem + si * 16384;

    const unsigned short* qrow = qg + (size_t)(b * SEQ + q0 + c) * HS;
    const short8 qa0 = *(const short8*)(qrow + quad * 8);
    const short8 qa1 = *(const short8*)(qrow + 32 + quad * 8);
    WAIT_VM0();   // drain Q loads so vmcnt counts ONLY our DMA below

    float m_st[4], l_st[4];
    f32x4 O[4];
#pragma unroll
    for (int r = 0; r < 4; ++r) { m_st[r] = -INFINITY; l_st[r] = 0.f; }
#pragma unroll
    for (int ht = 0; ht < 4; ++ht) O[ht] = (f32x4){0.f, 0.f, 0.f, 0.f};

    const int nTilesTot = (q0 + 16 + 31) >> 5;          // 32-key tiles (causal)
    const int nT = (nTilesTot - si + 3) >> 2;           // this wave's tile count

    auto issue = [&](int j, int p) {
        const int key0 = (si + 4 * j) * 32;
        const unsigned short* kgb = kg + (size_t)(b * SEQ + key0) * HS;
        char* dstK = kv + p * 8192;
#pragma unroll
        for (int i = 0; i < 4; ++i) {            // K[32 keys][64 h]
            const int f = i * 64 + lane, row = f >> 3, ch = f & 7;
            gll16(kgb + (size_t)row * HS + ((ch ^ (row & 7)) * 8), dstK + i * 1024);
        }
        const unsigned short* vgb = vtg + ((size_t)b << 17) + key0;
        char* dstV = kv + p * 8192 + 4096;
#pragma unroll
        for (int i = 0; i < 4; ++i) {            // V^T[64 h][32 t]
            const int f = i * 64 + lane, h = f >> 2, ch = f & 3;
            const int cs = ch ^ (h & 3) ^ ((h >> 2) & 3);
            gll16(vgb + ((size_t)h << 11) + cs * 8, dstV + i * 1024);
        }
    };

    if (nT > 0) issue(0, 0);
    if (nT > 1) issue(1, 1);

    for (int j = 0; j < nT; ++j) {
        if (j + 1 < nT) { WAIT_VM8(); } else { WAIT_VM0(); }   // tile j landed
        const int st = si + 4 * j, key0 = st * 32, p = j & 1;
        const unsigned short* Kb = (const unsigned short*)(kv + p * 8192);
        const unsigned short* Vb = (const unsigned short*)(kv + p * 8192 + 4096);
        const bool masked = (st == nTilesTot - 1);

        f32x4 sc[2];
#pragma unroll
        for (int nt = 0; nt < 2; ++nt) {
            const int kr = nt * 16 + c;
            short8 kb0 = *(const short8*)(Kb + kr * 64 + ((quad)     ^ (kr & 7)) * 8);
            short8 kb1 = *(const short8*)(Kb + kr * 64 + ((4 + quad) ^ (kr & 7)) * 8);
            f32x4 s = (f32x4){0.f, 0.f, 0.f, 0.f};
            s = __builtin_amdgcn_mfma_f32_16x16x32_bf16(qa0, kb0, s, 0, 0, 0);
            s = __builtin_amdgcn_mfma_f32_16x16x32_bf16(qa1, kb1, s, 0, 0, 0);
            sc[nt] = s * 0.125f;
            if (masked) {
                const int sglob = key0 + kr;
#pragma unroll
                for (int r = 0; r < 4; ++r)
                    if (sglob > q0 + quad * 4 + r) sc[nt][r] = -INFINITY;
            }
        }
#pragma unroll
        for (int r = 0; r < 4; ++r) {
            float v = fmaxf(sc[0][r], sc[1][r]);
            v = fmaxf(v, __shfl_xor(v, 1));
            v = fmaxf(v, __shfl_xor(v, 2));
            v = fmaxf(v, __shfl_xor(v, 4));
            v = fmaxf(v, __shfl_xor(v, 8));
            const float mnew  = fmaxf(m_st[r], v);
            const float alpha = __expf(m_st[r] - mnew);
            const float p0 = __expf(sc[0][r] - mnew);
            const float p1 = __expf(sc[1][r] - mnew);
            float sum = p0 + p1;
            sum += __shfl_xor(sum, 1);
            sum += __shfl_xor(sum, 2);
            sum += __shfl_xor(sum, 4);
            sum += __shfl_xor(sum, 8);
            l_st[r] = l_st[r] * alpha + sum;
            m_st[r] = mnew;
#pragma unroll
            for (int ht = 0; ht < 4; ++ht) O[ht][r] *= alpha;
            const int prow = si * 16 + quad * 4 + r;
            Ps[prow][c]      = f2bf(p0);
            Ps[prow][16 + c] = f2bf(p1);
        }
        short8 pa = *(const short8*)&Ps[si * 16 + c][quad * 8];
#pragma unroll
        for (int ht = 0; ht < 4; ++ht) {
            const int vr  = ht * 16 + c;
            const int pos = quad ^ (vr & 3) ^ ((vr >> 2) & 3);
            short8 vb = *(const short8*)(Vb + vr * 32 + pos * 8);
            O[ht] = __builtin_amdgcn_mfma_f32_16x16x32_bf16(pa, vb, O[ht], 0, 0, 0);
        }
        WAIT_LGKM0();                       // ds reads done before buf reuse
        if (j + 2 < nT) issue(j + 2, p);    // prefetch into the buf just freed
    }

    // ---- cross-wave combine (the only barriers in the kernel) ----
    if (c == 0) {
#pragma unroll
        for (int r = 0; r < 4; ++r) {
            msl[si * 16 + quad * 4 + r]      = m_st[r];
            msl[64 + si * 16 + quad * 4 + r] = l_st[r];
        }
    }
    __syncthreads();
#pragma unroll
    for (int r = 0; r < 4; ++r) {
        const int row = quad * 4 + r;
        float M = fmaxf(fmaxf(msl[row], msl[16 + row]),
                        fmaxf(msl[32 + row], msl[48 + row]));
        const float scw = __expf(m_st[r] - M);   // 0 for idle waves (m=-inf)
#pragma unroll
        for (int ht = 0; ht < 4; ++ht)
            Oc[si * 16 + row][ht * 16 + c] = O[ht][r] * scw;
    }
    __syncthreads();
    {
        const int row = tid >> 4, hb = (tid & 15) * 4;
        float M = fmaxf(fmaxf(msl[row], msl[16 + row]),
                        fmaxf(msl[32 + row], msl[48 + row]));
        float L = 0.f;
#pragma unroll
        for (int w = 0; w < 4; ++w)
            L += __expf(msl[w * 16 + row] - M) * msl[64 + w * 16 + row];
        float ax = 0.f, ay = 0.f, az = 0.f, aw = 0.f;
#pragma unroll
        for (int w = 0; w < 4; ++w) {
            const float4 t = *(const float4*)&Oc[w * 16 + row][hb];
            ax += t.x; ay += t.y; az += t.z; aw += t.w;
        }
        const float inv = 1.f / L;
        *(float4*)(out + (size_t)(b * SEQ + q0 + row) * HS + hb) =
            make_float4(ax * inv, ay * inv, az * inv, aw * inv);
    }
}

// ---------------------------------------------------------------------------
extern "C" void kernel_launch(void* const* d_in, const int* in_sizes, int n_in,
                              void* d_out, int out_size, void* d_ws, size_t ws_size,
                              hipStream_t stream)
{
    const float* x  = (const float*)d_in[0];
    const float* Wq = (const float*)d_in[1];
    const float* Wk = (const float*)d_in[2];
    const float* Wv = (const float*)d_in[3];

    // ws: q | k | v^T (bf16, 1 MB each) | x tiled bf16 (16 MB) | W tiled bf16 (384 KB)
    unsigned short* qb  = (unsigned short*)d_ws;
    unsigned short* kb  = qb  + (size_t)BATCH * SEQ * HS;
    unsigned short* vtb = kb  + (size_t)BATCH * SEQ * HS;
    unsigned short* xbt = vtb + (size_t)BATCH * SEQ * HS;
    unsigned short* wt  = xbt + (size_t)BATCH * SEQ * NEMB;

    pack_tiles<<<dim3(524),           dim3(256), 0, stream>>>(x, Wq, Wk, Wv, xbt, wt);
    qkv_proj  <<<dim3(BATCH*SEQ/16),  dim3(256), 0, stream>>>(xbt, wt, qb, kb, vtb);
    attn      <<<dim3(SEQ/16, BATCH), dim3(256), 0, stream>>>(qb, kb, vtb, (float*)d_out);
}

// Round 7
// 125.041 us; speedup vs baseline: 1.1782x; 1.1029x over previous
//
#include <hip/hip_runtime.h>
#include <math.h>

// Problem constants (fixed by the reference).
constexpr int BATCH = 4;
constexpr int SEQ   = 2048;
constexpr int NEMB  = 1024;
constexpr int HS    = 64;

typedef __attribute__((ext_vector_type(8))) short short8;   // MFMA A/B frag (8 bf16)
typedef __attribute__((ext_vector_type(4))) float f32x4;    // MFMA C/D frag
typedef __attribute__((ext_vector_type(4))) float fv4;      // native vec for NT loads

// fp32 -> bf16 bits, round-to-nearest-even
__device__ inline unsigned short f2bf(float f) {
    unsigned u = __builtin_bit_cast(unsigned, f);
    u += 0x7fffu + ((u >> 16) & 1u);
    return (unsigned short)(u >> 16);
}
__device__ inline unsigned long long pack4bf(float a, float b, float c, float d) {
    return (unsigned long long)(f2bf(a) | ((unsigned)f2bf(b) << 16)) |
           ((unsigned long long)(f2bf(c) | ((unsigned)f2bf(d) << 16)) << 32);
}

// ---------------------------------------------------------------------------
// Kernel 0: W fp32 -> fragment-tiled bf16. wt = 12 n-tiles (q|k|v heads, 4
// each); tile layout: elem (kc, r, j) at elem offset (kc*16+r)*8+j, where the
// original element is (row = tile*16 + r, k = kc*8 + j).
// ---------------------------------------------------------------------------
__launch_bounds__(256) __global__
void conv_w(const float* __restrict__ Wq, const float* __restrict__ Wk,
            const float* __restrict__ Wv, unsigned short* __restrict__ wt)
{
    const int wi = blockIdx.x;         // n-tile 0..11
    const int t  = threadIdx.x;
    char* dst = (char*)(wt + (size_t)wi * 16384);
    const int sel = wi >> 2;
    const float* W = (sel == 0) ? Wq : (sel == 1) ? Wk : Wv;
    const size_t woff = (size_t)(t >> 1) * 256 + (t & 1) * 8;
#pragma unroll 4
    for (int i = 0; i < 16; ++i) {
        const float* src = W + (size_t)((wi & 3) * 16 + i) * NEMB;
        fv4 v = __builtin_nontemporal_load((const fv4*)src + t);
        *(unsigned long long*)(dst + woff + (size_t)i * 16) =
            pack4bf(v.x, v.y, v.z, v.w);
    }
}

// ---------------------------------------------------------------------------
// Kernel 1: QKV projection. Block bid -> x rows [16*bid, 16*bid+16).
// Stage x slice into LDS in swizzled fragment layout:
//   elem (kc, r, j) at byte 256*kc + 16*((r+kc)&15) + 2*j  (write & read both
//   <=2-way bank aliasing; swizzle breaks the 256B stride).
// K-loop per wave: 1 ds_read_b128 (A) + 3 contiguous 1KB wave-loads (B from
// L2-resident wt) + 3 MFMA, no barriers. One __syncthreads after staging.
// Outputs q,k bf16 [bt][64]; v bf16 transposed [b][h][t].
// ---------------------------------------------------------------------------
__launch_bounds__(256) __global__
void qkv_proj(const float* __restrict__ x, const unsigned short* __restrict__ wt,
              unsigned short* __restrict__ qb, unsigned short* __restrict__ kb,
              unsigned short* __restrict__ vtb)
{
    __shared__ __align__(16) char smem[32768];
    const int bid  = blockIdx.x;
    const int tid  = threadIdx.x;
    const int si   = tid >> 6;        // wave index
    const int lane = tid & 63;
    const int quad = lane >> 4;
    const int c    = lane & 15;
    const int m0   = bid * 16;

    // stage x tile (16 rows x 1024 fp32) -> swizzled bf16 fragment layout
#pragma unroll 4
    for (int i = 0; i < 16; ++i) {
        float4 v = *(const float4*)(x + (size_t)(m0 + i) * NEMB + tid * 4);
        const int kc = tid >> 1;
        char* p = smem + 256 * kc + 16 * ((i + kc) & 15) + (tid & 1) * 8;
        *(unsigned long long*)p = pack4bf(v.x, v.y, v.z, v.w);
    }
    __syncthreads();

    f32x4 acc[3];
#pragma unroll
    for (int j = 0; j < 3; ++j) acc[j] = (f32x4){0.f, 0.f, 0.f, 0.f};

    const unsigned short* bb = wt + (size_t)(si * 3) * 16384 + quad * 128 + c * 8;
#pragma unroll 4
    for (int kc0 = 0; kc0 < 128; kc0 += 4) {        // K-step 32
        const int kcq = kc0 + quad;
        short8 a = *(const short8*)(smem + 256 * kcq + 16 * ((c + kcq) & 15));
#pragma unroll
        for (int j = 0; j < 3; ++j) {
            short8 bf = *(const short8*)(bb + (size_t)j * 16384 + (size_t)kc0 * 128);
            acc[j] = __builtin_amdgcn_mfma_f32_16x16x32_bf16(a, bf, acc[j], 0, 0, 0);
        }
    }

    // Epilogue. C layout: row = quad*4+reg (m), col = c (n).
    const int mrow = m0 + quad * 4;
#pragma unroll
    for (int j = 0; j < 3; ++j) {
        const int n = si * 48 + j * 16 + c;
        if (n < 128) {          // q or k: row-major [bt][64] bf16
            unsigned short* dst = (n < 64) ? (qb + n) : (kb + (n - 64));
#pragma unroll
            for (int r = 0; r < 4; ++r)
                dst[(size_t)(mrow + r) * HS] = f2bf(acc[j][r]);
        } else {                // v: transposed [b][h][t] bf16, 4 consecutive t
            const int h  = n - 128;
            const int b2 = mrow >> 11;
            const int t0 = mrow & 2047;
            *(unsigned long long*)(vtb + ((size_t)b2 << 17) + ((size_t)h << 11) + t0) =
                pack4bf(acc[j][0], acc[j][1], acc[j][2], acc[j][3]);
        }
    }
}

// ---------------------------------------------------------------------------
// Kernel 2: MFMA flash attention — K/V read DIRECTLY from global (L2).
// K (256 KB/batch) and V^T (256 KB/batch) are L2-resident; fragment loads
// are b128 from global with the exact same lane math as the old LDS path.
// No staging, no DMA, no vmcnt asm, no K-loop barriers; LDS only for the
// P C->A transform (per-wave region) and the final combine. 17.9 KB LDS ->
// many blocks/CU -> real latency hiding. Wave si owns 32-key tiles
// st == si (mod 4) with private online-softmax state.
// ---------------------------------------------------------------------------
__launch_bounds__(256) __global__
void attn(const unsigned short* __restrict__ qg, const unsigned short* __restrict__ kg,
          const unsigned short* __restrict__ vtg, float* __restrict__ out)
{
    __shared__ __align__(16) char smem[17920];
    auto Ps  = (unsigned short(*)[40])smem;       // [64][40] bf16 (5120 B), loop-live
    auto Oc  = (float(*)[68])smem;                // [64][68] fp32 (17408 B), end-live
    float* msl = (float*)(smem + 17408);          // m[4][16] | l[4][16] (512 B)

    const int b    = blockIdx.y;
    const int qt   = (int)gridDim.x - 1 - (int)blockIdx.x;  // heavy tiles first
    const int q0   = qt * 16;
    const int tid  = threadIdx.x;
    const int si   = tid >> 6;
    const int lane = tid & 63;
    const int quad = lane >> 4;
    const int c    = lane & 15;

    // Q fragments in registers for the whole kernel. A[m=c][k=quad*8+j].
    const unsigned short* qrow = qg + (size_t)(b * SEQ + q0 + c) * HS;
    const short8 qa0 = *(const short8*)(qrow + quad * 8);
    const short8 qa1 = *(const short8*)(qrow + 32 + quad * 8);

    const unsigned short* kbase = kg + (size_t)b * SEQ * HS;
    const unsigned short* vbase = vtg + ((size_t)b << 17);

    float m_st[4], l_st[4];
    f32x4 O[4];
#pragma unroll
    for (int r = 0; r < 4; ++r) { m_st[r] = -INFINITY; l_st[r] = 0.f; }
#pragma unroll
    for (int ht = 0; ht < 4; ++ht) O[ht] = (f32x4){0.f, 0.f, 0.f, 0.f};

    const int nTilesTot = (q0 + 16 + 31) >> 5;          // 32-key tiles (causal)

    for (int st = si; st < nTilesTot; st += 4) {
        const int key0 = st * 32;
        const bool masked = (st == nTilesTot - 1);

        // ---- S = Q K^T * scale; B-frag rows straight from global (L2) ----
        f32x4 sc[2];
#pragma unroll
        for (int nt = 0; nt < 2; ++nt) {
            const int kr = nt * 16 + c;                 // key within tile
            const unsigned short* krow = kbase + (size_t)(key0 + kr) * HS;
            short8 kb0 = *(const short8*)(krow + quad * 8);
            short8 kb1 = *(const short8*)(krow + 32 + quad * 8);
            f32x4 s = (f32x4){0.f, 0.f, 0.f, 0.f};
            s = __builtin_amdgcn_mfma_f32_16x16x32_bf16(qa0, kb0, s, 0, 0, 0);
            s = __builtin_amdgcn_mfma_f32_16x16x32_bf16(qa1, kb1, s, 0, 0, 0);
            sc[nt] = s * 0.125f;
            if (masked) {
                const int sglob = key0 + kr;
#pragma unroll
                for (int r = 0; r < 4; ++r)
                    if (sglob > q0 + quad * 4 + r) sc[nt][r] = -INFINITY;
            }
        }
        // ---- online softmax per row (reduce across 16 lanes of the quad) ----
#pragma unroll
        for (int r = 0; r < 4; ++r) {
            float v = fmaxf(sc[0][r], sc[1][r]);
            v = fmaxf(v, __shfl_xor(v, 1));
            v = fmaxf(v, __shfl_xor(v, 2));
            v = fmaxf(v, __shfl_xor(v, 4));
            v = fmaxf(v, __shfl_xor(v, 8));
            const float mnew  = fmaxf(m_st[r], v);
            const float alpha = __expf(m_st[r] - mnew);
            const float p0 = __expf(sc[0][r] - mnew);
            const float p1 = __expf(sc[1][r] - mnew);
            float sum = p0 + p1;
            sum += __shfl_xor(sum, 1);
            sum += __shfl_xor(sum, 2);
            sum += __shfl_xor(sum, 4);
            sum += __shfl_xor(sum, 8);
            l_st[r] = l_st[r] * alpha + sum;
            m_st[r] = mnew;
#pragma unroll
            for (int ht = 0; ht < 4; ++ht) O[ht][r] *= alpha;
            const int prow = si * 16 + quad * 4 + r;    // wave-private P region
            Ps[prow][c]      = f2bf(p0);
            Ps[prow][16 + c] = f2bf(p1);
        }
        // ---- O += P V : A = P via LDS transform; B = V^T rows from global ----
        short8 pa = *(const short8*)&Ps[si * 16 + c][quad * 8];
#pragma unroll
        for (int ht = 0; ht < 4; ++ht) {
            const int vr = ht * 16 + c;                 // h row of V^T
            short8 vb = *(const short8*)(vbase + ((size_t)vr << 11) + key0 + quad * 8);
            O[ht] = __builtin_amdgcn_mfma_f32_16x16x32_bf16(pa, vb, O[ht], 0, 0, 0);
        }
        // per-wave Ps region: in-order DS ops within a wave make the next
        // tile's ds_write safe after this tile's pa ds_read (no barrier).
    }

    // ---- cross-wave combine (the only barriers in the kernel) ----
    if (c == 0) {
#pragma unroll
        for (int r = 0; r < 4; ++r) {
            msl[si * 16 + quad * 4 + r]      = m_st[r];
            msl[64 + si * 16 + quad * 4 + r] = l_st[r];
        }
    }
    __syncthreads();
#pragma unroll
    for (int r = 0; r < 4; ++r) {
        const int row = quad * 4 + r;
        float M = fmaxf(fmaxf(msl[row], msl[16 + row]),
                        fmaxf(msl[32 + row], msl[48 + row]));
        const float scw = __expf(m_st[r] - M);   // 0 for idle waves (m=-inf)
#pragma unroll
        for (int ht = 0; ht < 4; ++ht)
            Oc[si * 16 + row][ht * 16 + c] = O[ht][r] * scw;   // clobbers Ps (dead)
    }
    __syncthreads();
    {
        const int row = tid >> 4, hb = (tid & 15) * 4;
        float M = fmaxf(fmaxf(msl[row], msl[16 + row]),
                        fmaxf(msl[32 + row], msl[48 + row]));
        float L = 0.f;
#pragma unroll
        for (int w = 0; w < 4; ++w)
            L += __expf(msl[w * 16 + row] - M) * msl[64 + w * 16 + row];
        float ax = 0.f, ay = 0.f, az = 0.f, aw = 0.f;
#pragma unroll
        for (int w = 0; w < 4; ++w) {
            const float4 t = *(const float4*)&Oc[w * 16 + row][hb];
            ax += t.x; ay += t.y; az += t.z; aw += t.w;
        }
        const float inv = 1.f / L;
        *(float4*)(out + (size_t)(b * SEQ + q0 + row) * HS + hb) =
            make_float4(ax * inv, ay * inv, az * inv, aw * inv);
    }
}

// ---------------------------------------------------------------------------
extern "C" void kernel_launch(void* const* d_in, const int* in_sizes, int n_in,
                              void* d_out, int out_size, void* d_ws, size_t ws_size,
                              hipStream_t stream)
{
    const float* x  = (const float*)d_in[0];
    const float* Wq = (const float*)d_in[1];
    const float* Wk = (const float*)d_in[2];
    const float* Wv = (const float*)d_in[3];

    // ws: q | k | v^T (bf16, 1 MB each) | W tiled bf16 (384 KB)
    unsigned short* qb  = (unsigned short*)d_ws;
    unsigned short* kb  = qb  + (size_t)BATCH * SEQ * HS;
    unsigned short* vtb = kb  + (size_t)BATCH * SEQ * HS;
    unsigned short* wt  = vtb + (size_t)BATCH * SEQ * HS;

    conv_w  <<<dim3(12),              dim3(256), 0, stream>>>(Wq, Wk, Wv, wt);
    qkv_proj<<<dim3(BATCH * SEQ / 16), dim3(256), 0, stream>>>(x, wt, qb, kb, vtb);
    attn    <<<dim3(SEQ / 16, BATCH), dim3(256), 0, stream>>>(qb, kb, vtb, (float*)d_out);
}